// Round 1
// baseline (83.203 us; speedup 1.0000x reference)
//
#include <hip/hip_runtime.h>
#include <hip/hip_bf16.h>

// KPConv collapses to: out[c,:] = sum_m s[c,m] * (x[src(c,m),:] @ W[m])
// with s[c,m] = sum of w over neighbors whose argmin kernel point == m.
// Stage 1: W fp32 [16][64][128] -> bf16 [16][128][64] (transposed) in ws.
// Stage 2: fused per-32-center block: edge weights -> s (LDS, atomic-free),
//          then MFMA bf16 GEMM (M=32 rows/block, N=128, K=1024, BK=64).

#define P 16
#define IN_F 64
#define OUT_F 128
#define NCC 8192
#define KPE 0.6666667f  // float(1.0/1.5), matches numpy f32 promotion

typedef short short8 __attribute__((ext_vector_type(8)));
typedef float floatx4 __attribute__((ext_vector_type(4)));

__device__ inline unsigned short f2bf(float f) {
    __hip_bfloat16 h = __float2bfloat16(f);
    return __builtin_bit_cast(unsigned short, h);
}

// W [m][i][n] fp32 -> Wb [m][n][i] bf16 (coalesced writes, strided reads; tiny)
__global__ __launch_bounds__(256) void kconv_w(const float* __restrict__ Wf,
                                               unsigned short* __restrict__ Wb) {
    int tg = blockIdx.x * 256 + threadIdx.x;   // 131072 total
    int m = tg >> 13;
    int n = (tg >> 6) & 127;
    int i = tg & 63;
    Wb[tg] = f2bf(Wf[(m * 64 + i) * 128 + n]);
}

__global__ __launch_bounds__(512) void kconv_main(
    const float* __restrict__ x, const float* __restrict__ pos,
    const int* __restrict__ esrc, const int* __restrict__ etgt,
    const float* __restrict__ kpts, const unsigned short* __restrict__ Wb,
    float* __restrict__ out)
{
    __shared__ float kps[48];
    __shared__ float wv[512];
    __shared__ int   nnv[512];
    __shared__ int   srcv[512];
    __shared__ float s_loc[512];                    // [32 centers][16 m]
    __shared__ __align__(16) unsigned short As[32 * 72];   // pad 64->72
    __shared__ __align__(16) unsigned short Bs[128 * 72];  // pad 64->72

    const int t  = threadIdx.x;
    const int c0 = blockIdx.x * 32;

    if (t < 48) kps[t] = kpts[t];

    // ---- per-edge: argmin kernel point + linear influence weight ----
    // Exact-rounding ops: must bit-match numpy's fp32 sq so argmin agrees.
    const int e   = c0 * P + t;                  // 512 edges per block
    const int src = esrc[e];
    const int tgt = etgt[e];
    float rx = __fsub_rn(pos[tgt * 3 + 0], pos[src * 3 + 0]);
    float ry = __fsub_rn(pos[tgt * 3 + 1], pos[src * 3 + 1]);
    float rz = __fsub_rn(pos[tgt * 3 + 2], pos[src * 3 + 2]);
    __syncthreads();                             // kps ready
    float best = 1e30f; int nn = 0;
#pragma unroll
    for (int k = 0; k < 16; ++k) {
        float dx = __fsub_rn(rx, kps[k * 3 + 0]);
        float dy = __fsub_rn(ry, kps[k * 3 + 1]);
        float dz = __fsub_rn(rz, kps[k * 3 + 2]);
        float sq = __fadd_rn(__fadd_rn(__fmul_rn(dx, dx), __fmul_rn(dy, dy)),
                             __fmul_rn(dz, dz));
        if (sq < best) { best = sq; nn = k; }    // strict < == first-min (np.argmin)
    }
    float w = fmaxf(__fsub_rn(1.0f, __fdiv_rn(__fsqrt_rn(best), KPE)), 0.0f);
    wv[t] = w; nnv[t] = nn; srcv[t] = src;
    __syncthreads();

    // ---- s[c,m] = sum of w where nn == m (atomic-free) ----
    {
        int cl = t >> 4, mm = t & 15;
        float sacc = 0.f;
#pragma unroll
        for (int n2 = 0; n2 < 16; ++n2) {
            int idx = cl * 16 + n2;
            sacc += (nnv[idx] == mm) ? wv[idx] : 0.f;
        }
        s_loc[t] = sacc;
    }
    __syncthreads();

    // ---- MFMA GEMM: 32x128 block tile, K loop over 16 kernel points ----
    const float4* x4 = reinterpret_cast<const float4*>(x);
    const uint4*  wb4 = reinterpret_cast<const uint4*>(Wb);  // 1024 uint4 per m
    const int ar = t >> 4, aq = t & 15;          // A-fill: row, quarter(4 floats)
    const int bn = t >> 3, bsg = t & 7;          // B-fill chunk 1
    const int bn2 = (t + 512) >> 3, bsg2 = (t + 512) & 7;    // B-fill chunk 2

    const int wave = t >> 6, lane = t & 63;
    const int quad = lane >> 4, l16 = lane & 15;
    const int rgi = wave & 1, cgi = wave >> 1;   // 2 row groups x 4 col groups
    const int aoff  = (rgi * 16 + l16) * 72;
    const int boff0 = (cgi * 32 + l16) * 72;
    const int boff1 = (cgi * 32 + 16 + l16) * 72;
    const int koff  = quad * 8;

    floatx4 acc0 = {0.f, 0.f, 0.f, 0.f};
    floatx4 acc1 = {0.f, 0.f, 0.f, 0.f};

    // software pipeline: prefetch m=0 operands into registers
    float4 xv = x4[srcv[ar * 16 + 0] * 16 + aq];
    uint4 bv0 = wb4[t];
    uint4 bv1 = wb4[t + 512];

    for (int m = 0; m < 16; ++m) {
        // write phase: A = bf16(s * x_row), B from pre-transposed Wb
        float sv = s_loc[ar * 16 + m];
        ushort4 av;
        av.x = f2bf(sv * xv.x); av.y = f2bf(sv * xv.y);
        av.z = f2bf(sv * xv.z); av.w = f2bf(sv * xv.w);
        *reinterpret_cast<ushort4*>(&As[ar * 72 + aq * 4]) = av;
        *reinterpret_cast<uint4*>(&Bs[bn  * 72 + bsg  * 8]) = bv0;
        *reinterpret_cast<uint4*>(&Bs[bn2 * 72 + bsg2 * 8]) = bv1;
        __syncthreads();

        if (m < 15) {   // prefetch next iteration (overlaps MFMA below)
            xv  = x4[srcv[ar * 16 + m + 1] * 16 + aq];
            bv0 = wb4[(m + 1) * 1024 + t];
            bv1 = wb4[(m + 1) * 1024 + t + 512];
        }

#pragma unroll
        for (int ks = 0; ks < 2; ++ks) {
            short8 a  = *reinterpret_cast<const short8*>(&As[aoff  + ks * 32 + koff]);
            short8 b0 = *reinterpret_cast<const short8*>(&Bs[boff0 + ks * 32 + koff]);
            acc0 = __builtin_amdgcn_mfma_f32_16x16x32_bf16(a, b0, acc0, 0, 0, 0);
            short8 b1 = *reinterpret_cast<const short8*>(&Bs[boff1 + ks * 32 + koff]);
            acc1 = __builtin_amdgcn_mfma_f32_16x16x32_bf16(a, b1, acc1, 0, 0, 0);
        }
        __syncthreads();
    }

    // ---- epilogue: C/D layout col=lane&15, row=quad*4+reg ----
    const int colbase = cgi * 32 + l16;
    const int rowbase = c0 + rgi * 16 + quad * 4;
#pragma unroll
    for (int v = 0; v < 4; ++v) {
        out[(rowbase + v) * 128 + colbase]      = acc0[v];
        out[(rowbase + v) * 128 + colbase + 16] = acc1[v];
    }
}

extern "C" void kernel_launch(void* const* d_in, const int* in_sizes, int n_in,
                              void* d_out, int out_size, void* d_ws, size_t ws_size,
                              hipStream_t stream) {
    const float* x    = (const float*)d_in[0];
    const float* pos  = (const float*)d_in[1];
    const int*   esrc = (const int*)d_in[2];
    const int*   etgt = (const int*)d_in[3];
    const float* kpts = (const float*)d_in[4];
    const float* Wf   = (const float*)d_in[5];
    float* out = (float*)d_out;
    unsigned short* Wb = (unsigned short*)d_ws;   // 262144 B

    hipLaunchKernelGGL(kconv_w, dim3(512), dim3(256), 0, stream, Wf, Wb);
    hipLaunchKernelGGL(kconv_main, dim3(NCC / 32), dim3(512), 0, stream,
                       x, pos, esrc, etgt, kpts, Wb, out);
}